// Round 5
// baseline (559.094 us; speedup 1.0000x reference)
//
#include <hip/hip_runtime.h>

// ============================================================================
// R7b: tile-pair decomposition — no scattered global access in any inner loop.
// (R7 with the min(int,unsigned) compile error fixed: all-int block math.)
// R4-R6 evidence: any kernel with a per-record scattered global load/store is
// invariant at ~220us (accum) / ~105us (scatter) regardless of occupancy
// (45->76%) or unroll (1->8): per-CU L1-miss-queue x L2 latency wall.
// R7: 32 bins x 3200 atoms, 528 bin-pair tiles. One record per edge
// ((li<<12)|lj; Newton's 3rd law makes orientation irrelevant). Exact-sized,
// tile-grouped record array built by count->prefix->place (no CAP slack, no
// overflow). Accum: one tile per block, posI+posJ staged in LDS, fI+fJ slabs
// in LDS, contiguous coalesced record stream, inner loop all-LDS. Flush to
// 32 atomic-free partial rows; reduce sums rows.
// ============================================================================

#define NBIN   32
#define BA     3200           // atoms per bin (32*3200 = 102400 >= 100000)
#define BF     (BA * 3)       // 9600 floats per bin slab
#define NT     528            // NBIN*(NBIN+1)/2 tiles
#define SEGS   512            // scatter segments/blocks
#define ROW_F  307200         // floats per partial row (= NBIN * BF)

// ---------------- old fallback path ----------------
#define NBINS      8
#define BIN_ATOMS  12800
#define BIN_F      (BIN_ATOMS * 3)
#define BLOCK      1024
#define MAXCHUNKS  32

typedef __attribute__((ext_vector_type(4))) int ivec4;

__device__ __forceinline__ ivec4 nt_load_i4(const int* p) {
    return __builtin_nontemporal_load((const ivec4*)p);
}
__device__ __forceinline__ void lds_fadd(float* p, float v) {
    __hip_atomic_fetch_add(p, v, __ATOMIC_RELAXED, __HIP_MEMORY_SCOPE_WORKGROUP);
}
__device__ __forceinline__ unsigned lds_uinc(unsigned* p) {
    return __hip_atomic_fetch_add(p, 1u, __ATOMIC_RELAXED, __HIP_MEMORY_SCOPE_WORKGROUP);
}

// tile id for bin pair (i<=j): t = i*(2*NBIN+1-i)/2 + (j-i)
__device__ __forceinline__ unsigned tile_of(unsigned bs, unsigned bd) {
    const unsigned i = min(bs, bd), j = max(bs, bd);
    return ((i * (2u * NBIN + 1u - i)) >> 1) + (j - i);
}

// ---------------------------------------------------------------------------
// K1: count records per (segment, tile).
// ---------------------------------------------------------------------------
__global__ __launch_bounds__(1024) void pf_count(
    const int* __restrict__ src, const int* __restrict__ dst,
    unsigned* __restrict__ cnt, int nEdges)
{
    __shared__ unsigned c[NT];
    const int t = threadIdx.x;
    const int bid = (int)blockIdx.x;
    if (t < NT) c[t] = 0;
    __syncthreads();

    const int eblk  = ((nEdges + SEGS - 1) / SEGS + 3) & ~3;
    const int ebeg  = bid * eblk;
    const int eend  = (ebeg + eblk < nEdges) ? (ebeg + eblk) : nEdges;
    const int i4beg = ebeg >> 2;
    const int i4end = eend >> 2;

    for (int i4 = i4beg + t; i4 < i4end; i4 += 1024) {
        const ivec4 s4 = nt_load_i4(src + 4 * i4);
        const ivec4 d4 = nt_load_i4(dst + 4 * i4);
        #pragma unroll
        for (int k = 0; k < 4; ++k) {
            const unsigned bs = (unsigned)s4[k] / BA;
            const unsigned bd = (unsigned)d4[k] / BA;
            lds_uinc(&c[tile_of(bs, bd)]);
        }
    }
    __syncthreads();
    if (t < NT) cnt[bid * NT + t] = c[t];
}

// ---------------------------------------------------------------------------
// K2: exclusive prefix -> per-(seg,tile) global base, tile-grouped layout.
// ---------------------------------------------------------------------------
__global__ __launch_bounds__(1024) void pf_prefix(
    const unsigned* __restrict__ cnt, unsigned* __restrict__ base,
    unsigned* __restrict__ tileStart)
{
    __shared__ unsigned colTot[NT], ts[NT + 1];
    const int t = threadIdx.x;
    if (t < NT) {
        unsigned run = 0;
        for (int s = 0; s < SEGS; ++s) {
            base[s * NT + t] = run;          // offset within tile
            run += cnt[s * NT + t];
        }
        colTot[t] = run;
    }
    __syncthreads();
    if (t == 0) {
        unsigned run = 0;
        for (int k = 0; k < NT; ++k) { ts[k] = run; run += colTot[k]; }
        ts[NT] = run;
    }
    __syncthreads();
    if (t < NT) {
        const unsigned add = ts[t];
        for (int s = 0; s < SEGS; ++s) base[s * NT + t] += add;
    }
    if (t <= NT) tileStart[t] = ts[t];
}

// ---------------------------------------------------------------------------
// K3: place records. rec = (li<<12)|lj, li in bin i=min, lj in bin j=max.
// Stores to a tile are consecutive indices -> self-coalescing.
// ---------------------------------------------------------------------------
__global__ __launch_bounds__(1024) void pf_place(
    const int* __restrict__ src, const int* __restrict__ dst,
    const unsigned* __restrict__ base, unsigned* __restrict__ recs, int nEdges)
{
    __shared__ unsigned cur[NT];
    const int t = threadIdx.x;
    const int bid = (int)blockIdx.x;
    if (t < NT) cur[t] = base[bid * NT + t];
    __syncthreads();

    const int eblk  = ((nEdges + SEGS - 1) / SEGS + 3) & ~3;
    const int ebeg  = bid * eblk;
    const int eend  = (ebeg + eblk < nEdges) ? (ebeg + eblk) : nEdges;
    const int i4beg = ebeg >> 2;
    const int i4end = eend >> 2;

    for (int i4 = i4beg + t; i4 < i4end; i4 += 1024) {
        const ivec4 s4 = nt_load_i4(src + 4 * i4);
        const ivec4 d4 = nt_load_i4(dst + 4 * i4);
        #pragma unroll
        for (int k = 0; k < 4; ++k) {
            const unsigned su = (unsigned)s4[k], du = (unsigned)d4[k];
            const unsigned bs = su / BA, bd = du / BA;
            unsigned a = su, b = du;
            if (bd < bs) { a = du; b = su; }       // a in bin i=min, b in bin j=max
            const unsigned i = min(bs, bd), j = max(bs, bd);
            const unsigned li = a - i * BA, lj = b - j * BA;
            const unsigned tl = ((i * (2u * NBIN + 1u - i)) >> 1) + (j - i);
            const unsigned idx = lds_uinc(&cur[tl]);
            recs[idx] = (li << 12) | lj;
        }
    }
}

// ---------------------------------------------------------------------------
// K4: per-tile accumulation — inner loop is 100% LDS + one coalesced stream.
// LDS: posI[9600] posJ[9600] fI[9600] fJ[9600] e[16] = 153,664 B.
// Diagonal tiles alias posJ->posI, fJ->fI.
// ---------------------------------------------------------------------------
__global__ __launch_bounds__(1024) void pf_accum2(
    const float* __restrict__ pos,
    const float* __restrict__ sigma_p, const float* __restrict__ eps_p,
    const unsigned* __restrict__ recs, const unsigned* __restrict__ tileStart,
    float* __restrict__ frep,        // [NBIN][ROW_F]
    float* __restrict__ erep,        // [NT]
    int nAtoms)
{
    extern __shared__ float sh[];
    const int t = threadIdx.x, lane = t & 63, v = t >> 6;

    // decode tile -> (i,j), uniform scalar
    int i = 0, rem = (int)blockIdx.x;
    while (rem >= NBIN - i) { rem -= NBIN - i; ++i; }
    const int j = i + rem;
    const bool diag = (i == j);

    float* sPosI = sh;
    float* sPosJ = diag ? sh : sh + BF;
    float* sFI   = sh + 2 * BF;
    float* sFJ   = diag ? sFI : sh + 3 * BF;
    float* sE    = sh + 4 * BF;

    // zero both force slabs + energy partials
    for (int k = t; k < (2 * BF + 16) / 4; k += 1024)
        ((float4*)(sh + 2 * BF))[k] = make_float4(0.f, 0.f, 0.f, 0.f);

    // stage positions (clamped to nAtoms)
    {
        const int aI = i * BA;
        int nf = nAtoms - aI; if (nf > BA) nf = BA; if (nf < 0) nf = 0; nf *= 3;
        const float* g = pos + (size_t)aI * 3;
        for (int k = t; k < (nf >> 2); k += 1024) ((float4*)sPosI)[k] = ((const float4*)g)[k];
        for (int k = (nf & ~3) + t; k < nf; k += 1024) sPosI[k] = g[k];
    }
    if (!diag) {
        const int aJ = j * BA;
        int nf = nAtoms - aJ; if (nf > BA) nf = BA; if (nf < 0) nf = 0; nf *= 3;
        const float* g = pos + (size_t)aJ * 3;
        for (int k = t; k < (nf >> 2); k += 1024) ((float4*)sPosJ)[k] = ((const float4*)g)[k];
        for (int k = (nf & ~3) + t; k < nf; k += 1024) sPosJ[k] = g[k];
    }
    __syncthreads();

    const float sigma = sigma_p[0], eps = eps_p[0];
    const float sig2 = sigma * sigma;
    const float c12 = 12.f * eps, c4 = 4.f * eps;

    const int rBeg = (int)tileStart[blockIdx.x];
    const int rEnd = (int)tileStart[blockIdx.x + 1];
    float ev = 0.f;

    for (int r0 = rBeg; r0 < rEnd; r0 += 4 * 1024) {
        unsigned rc[4]; bool ac[4];
        #pragma unroll
        for (int k = 0; k < 4; ++k) {
            const int idx = r0 + k * 1024 + t;
            ac[k] = idx < rEnd;
            rc[k] = ac[k] ? recs[idx] : 0u;
        }
        #pragma unroll
        for (int k = 0; k < 4; ++k) {
            const int li = rc[k] >> 12, lj = rc[k] & 0xFFF;
            const float ax = sPosI[3 * li + 0], ay = sPosI[3 * li + 1], az = sPosI[3 * li + 2];
            const float bx = sPosJ[3 * lj + 0], by = sPosJ[3 * lj + 1], bz = sPosJ[3 * lj + 2];
            const float dx = ax - bx, dy = ay - by, dz = az - bz;
            const float r2   = dx * dx + dy * dy + dz * dz;
            const float ir2  = 1.0f / r2;
            const float s2   = sig2 * ir2;
            const float sr6  = s2 * s2 * s2;
            const float sr12 = sr6 * sr6;
            const float fs   = c12 * (2.f * sr12 - sr6) * ir2;
            if (ac[k]) {
                lds_fadd(&sFI[3 * li + 0],  fs * dx);
                lds_fadd(&sFI[3 * li + 1],  fs * dy);
                lds_fadd(&sFI[3 * li + 2],  fs * dz);
                lds_fadd(&sFJ[3 * lj + 0], -fs * dx);
                lds_fadd(&sFJ[3 * lj + 1], -fs * dy);
                lds_fadd(&sFJ[3 * lj + 2], -fs * dz);
                ev += c4 * (sr12 - sr6);      // one record per directed edge
            }
        }
    }

    #pragma unroll
    for (int off = 32; off > 0; off >>= 1) ev += __shfl_down(ev, off, 64);
    if (lane == 0) sE[v] = ev;
    __syncthreads();

    // flush: fI -> (row j, bin i); fJ -> (row i, bin j). Diagonal: fI only.
    float4* dI = (float4*)(frep + (size_t)j * ROW_F + (size_t)i * BF);
    for (int k = t; k < BF / 4; k += 1024) dI[k] = ((float4*)sFI)[k];
    if (!diag) {
        float4* dJ = (float4*)(frep + (size_t)i * ROW_F + (size_t)j * BF);
        for (int k = t; k < BF / 4; k += 1024) dJ[k] = ((float4*)sFJ)[k];
    }
    if (t == 0) {
        float e = 0.f;
        #pragma unroll
        for (int w = 0; w < 16; ++w) e += sE[w];
        erep[blockIdx.x] = e;
    }
}

// ---------------------------------------------------------------------------
// Shared reduce kernel (rows -> output).
// ---------------------------------------------------------------------------
__global__ __launch_bounds__(256) void pairforce_reduce(
    const float* __restrict__ frep,
    const float* __restrict__ erep,
    float* __restrict__ out,          // [0]=energy, [1..n3]=forces
    int n3, int nChunks, int nPart)
{
    const int i = blockIdx.x * 256 + threadIdx.x;
    if (i < n3) {
        float acc = 0.f;
        for (int c = 0; c < nChunks; ++c)
            acc += frep[(size_t)c * ROW_F + i];
        out[1 + i] = acc;
    }
    if (blockIdx.x == gridDim.x - 1) {      // energy fold
        float e = 0.f;
        for (int jj = threadIdx.x; jj < nPart; jj += 256) e += erep[jj];
        #pragma unroll
        for (int off = 32; off > 0; off >>= 1) e += __shfl_down(e, off, 64);
        __shared__ float ep[4];
        if ((threadIdx.x & 63) == 0) ep[threadIdx.x >> 6] = e;
        __syncthreads();
        if (threadIdx.x == 0) out[0] = ep[0] + ep[1] + ep[2] + ep[3];
    }
}

// ---------------------------------------------------------------------------
// Fallback: R3's binned kernel, verbatim (used only if guards fail).
// ---------------------------------------------------------------------------
__global__ __launch_bounds__(BLOCK, 1) void pairforce_binned(
    const float* __restrict__ pos,
    const float* __restrict__ sigma_p,
    const float* __restrict__ eps_p,
    const int*   __restrict__ src,
    const int*   __restrict__ dst,
    float* __restrict__ frep,
    float* __restrict__ erep,
    int nEdges, int chunkEdges)
{
    extern __shared__ float sh[];
    const int t = threadIdx.x;
    const int b = blockIdx.x % NBINS;
    const int c = blockIdx.x / NBINS;

    for (int jj = t; jj < (BIN_F + 16) / 4; jj += BLOCK)
        ((float4*)sh)[jj] = make_float4(0.f, 0.f, 0.f, 0.f);
    __syncthreads();

    const float sigma = sigma_p[0];
    const float eps   = eps_p[0];
    const float sig2  = sigma * sigma;
    const int binStart = b * BIN_ATOMS;

    const int start = c * chunkEdges;
    const int end   = min(start + chunkEdges, nEdges);

    const int4* src4 = (const int4*)src;
    const int4* dst4 = (const int4*)dst;

    float ev = 0.0f;

    for (int i4 = (start >> 2) + t; i4 < (end >> 2); i4 += BLOCK) {
        const int4 s4 = src4[i4];
        const int4 d4 = dst4[i4];
        #pragma unroll
        for (int k = 0; k < 4; ++k) {
            const int s = (k == 0) ? s4.x : (k == 1) ? s4.y : (k == 2) ? s4.z : s4.w;
            const int d = (k == 0) ? d4.x : (k == 1) ? d4.y : (k == 2) ? d4.z : d4.w;
            const unsigned ls = (unsigned)(s - binStart);
            const unsigned ld = (unsigned)(d - binStart);
            const bool hs = ls < BIN_ATOMS;
            const bool hd = ld < BIN_ATOMS;
            if (hs | hd) {
                const float dx = pos[3 * s + 0] - pos[3 * d + 0];
                const float dy = pos[3 * s + 1] - pos[3 * d + 1];
                const float dz = pos[3 * s + 2] - pos[3 * d + 2];
                const float r2     = dx * dx + dy * dy + dz * dz;
                const float inv_r2 = 1.0f / r2;
                const float s2     = sig2 * inv_r2;
                const float sr6    = s2 * s2 * s2;
                const float sr12   = sr6 * sr6;
                const float fs = 12.0f * eps * (2.0f * sr12 - sr6) * inv_r2;
                const float fx = fs * dx;
                const float fy = fs * dy;
                const float fz = fs * dz;
                if (hs) {
                    atomicAdd(&sh[3 * ls + 0],  fx);
                    atomicAdd(&sh[3 * ls + 1],  fy);
                    atomicAdd(&sh[3 * ls + 2],  fz);
                    ev += 4.0f * eps * (sr12 - sr6);
                }
                if (hd) {
                    atomicAdd(&sh[3 * ld + 0], -fx);
                    atomicAdd(&sh[3 * ld + 1], -fy);
                    atomicAdd(&sh[3 * ld + 2], -fz);
                }
            }
        }
    }

    #pragma unroll
    for (int off = 32; off > 0; off >>= 1)
        ev += __shfl_down(ev, off, 64);
    if ((t & 63) == 0) sh[BIN_F + (t >> 6)] = ev;
    __syncthreads();

    float4* outSeg = (float4*)(frep + (size_t)c * ROW_F + (size_t)b * BIN_F);
    for (int jj = t; jj < BIN_F / 4; jj += BLOCK)
        outSeg[jj] = ((float4*)sh)[jj];

    if (t == 0) {
        float e = 0.f;
        #pragma unroll
        for (int w = 0; w < 16; ++w) e += sh[BIN_F + w];
        erep[blockIdx.x] = e;
    }
}

extern "C" void kernel_launch(void* const* d_in, const int* in_sizes, int n_in,
                              void* d_out, int out_size, void* d_ws, size_t ws_size,
                              hipStream_t stream)
{
    const float* pos     = (const float*)d_in[0];
    const float* sigma_p = (const float*)d_in[1];
    const float* eps_p   = (const float*)d_in[2];
    const int*   edge    = (const int*)d_in[3];

    const int nEdges = in_sizes[3] / 2;      // edge_index is [2, E]
    const int* src = edge;
    const int* dst = edge + nEdges;

    const int n3 = out_size - 1;             // 3*N
    const int nAtoms = n3 / 3;

    // ---- new-path workspace layout (~66 MB, proven >=88.5 MB available) ----
    auto alignup = [](size_t x) { return (x + 255) & ~(size_t)255; };
    size_t off = 0;
    unsigned* recs   = (unsigned*)((char*)d_ws + off); off = alignup(off + (size_t)nEdges * 4);
    unsigned* cntp   = (unsigned*)((char*)d_ws + off); off = alignup(off + (size_t)SEGS * NT * 4);
    unsigned* basep  = (unsigned*)((char*)d_ws + off); off = alignup(off + (size_t)SEGS * NT * 4);
    unsigned* tstart = (unsigned*)((char*)d_ws + off); off = alignup(off + (size_t)(NT + 1) * 4);
    float*    frepN  = (float*)((char*)d_ws + off);    off = alignup(off + (size_t)NBIN * ROW_F * 4);
    float*    erepN  = (float*)((char*)d_ws + off);    off = alignup(off + (size_t)NT * 4);

    if (ws_size >= off && nAtoms <= NBIN * BA && nEdges > 0 && (nEdges & 3) == 0) {
        pf_count<<<SEGS, 1024, 0, stream>>>(src, dst, cntp, nEdges);
        pf_prefix<<<1, 1024, 0, stream>>>(cntp, basep, tstart);
        pf_place<<<SEGS, 1024, 0, stream>>>(src, dst, basep, recs, nEdges);
        const size_t shb = (size_t)(4 * BF + 16) * sizeof(float);   // 153,664 B
        pf_accum2<<<NT, 1024, shb, stream>>>(pos, sigma_p, eps_p, recs, tstart,
                                             frepN, erepN, nAtoms);
        pairforce_reduce<<<(n3 + 255) / 256, 256, 0, stream>>>(
            frepN, erepN, (float*)d_out, n3, NBIN, NT);
        return;
    }

    // ---- fallback: R3 path ----
    const size_t rowBytes = (size_t)ROW_F * sizeof(float);
    int nChunks = (int)((ws_size - 4096) / rowBytes);
    if (nChunks > MAXCHUNKS) nChunks = MAXCHUNKS;
    if (nChunks < 1) nChunks = 1;

    const int chunkEdges = (((nEdges + nChunks - 1) / nChunks) + 3) & ~3;

    float* frep = (float*)d_ws;
    float* erep = frep + (size_t)nChunks * ROW_F;

    const size_t shbytes = (size_t)(BIN_F + 16) * sizeof(float);

    const int grid1 = nChunks * NBINS;
    pairforce_binned<<<grid1, BLOCK, shbytes, stream>>>(
        pos, sigma_p, eps_p, src, dst, frep, erep, nEdges, chunkEdges);

    const int grid2 = (n3 + 255) / 256;
    pairforce_reduce<<<grid2, 256, 0, stream>>>(
        frep, erep, (float*)d_out, n3, nChunks, nChunks * NBINS);
}

// Round 6
// 501.504 us; speedup vs baseline: 1.1148x; 1.1148x over previous
//
#include <hip/hip_runtime.h>

// ============================================================================
// R8: R7b tile-pair structure with the accum DS-chain broken.
// R7b evidence: accum2 274us, VALUBusy 3.3%, VGPR=12 -> compiler serialized
// the loop because LDS pos-reads after LDS force-atomics may-alias (same
// extern-shared blob, dynamic offsets); plus 528 blocks @1/CU = 3-round tail.
// R8 accum: uint4 record loads (+1 prefetch), ALL 24 LDS reads into arrays
// BEFORE compute, atomics last (program order == legal order -> pipelined);
// launch_bounds(1024,1); grid=512 exactly (32 diagonal tiles merged pairwise,
// 2 slab-select bits per record). count/prefix/place/reduce unchanged.
// ============================================================================

#define NBIN   32
#define BA     3200           // atoms per bin (32*3200 = 102400 >= 100000)
#define BF     (BA * 3)       // 9600 floats per bin slab
#define NBK    512            // buckets: 496 off-diag tiles + 16 merged diag pairs
#define SEGS   512            // edge segments
#define ROW_F  307200         // floats per partial row (= NBIN * BF)

// ---------------- old fallback path ----------------
#define NBINS      8
#define BIN_ATOMS  12800
#define BIN_F      (BIN_ATOMS * 3)
#define BLOCK      1024
#define MAXCHUNKS  32

typedef __attribute__((ext_vector_type(4))) int ivec4;

__device__ __forceinline__ ivec4 nt_load_i4(const int* p) {
    return __builtin_nontemporal_load((const ivec4*)p);
}
__device__ __forceinline__ void lds_fadd(float* p, float v) {
    __hip_atomic_fetch_add(p, v, __ATOMIC_RELAXED, __HIP_MEMORY_SCOPE_WORKGROUP);
}
__device__ __forceinline__ unsigned lds_uinc(unsigned* p) {
    return __hip_atomic_fetch_add(p, 1u, __ATOMIC_RELAXED, __HIP_MEMORY_SCOPE_WORKGROUP);
}

// bucket for bin pair: off-diag (i<j) -> i*(63-i)/2 + (j-i-1)  [0..495]
// diag (i,i) -> 496 + i/2  (pairs (2k,2k) & (2k+1,2k+1) merged)
__device__ __forceinline__ unsigned bucket_of(unsigned bs, unsigned bd) {
    const unsigned i = min(bs, bd), j = max(bs, bd);
    return (i == j) ? (496u + (i >> 1)) : ((i * (63u - i)) >> 1) + (j - i - 1u);
}

// ---------------------------------------------------------------------------
// K1: count records per (segment, bucket).
// ---------------------------------------------------------------------------
__global__ __launch_bounds__(1024) void pf_count(
    const int* __restrict__ src, const int* __restrict__ dst,
    unsigned* __restrict__ cnt, int nEdges)
{
    __shared__ unsigned c[NBK];
    const int t = threadIdx.x;
    const int bid = (int)blockIdx.x;
    if (t < NBK) c[t] = 0;
    __syncthreads();

    const int eblk  = ((nEdges + SEGS - 1) / SEGS + 3) & ~3;
    const int ebeg  = bid * eblk;
    const int eend  = (ebeg + eblk < nEdges) ? (ebeg + eblk) : nEdges;
    const int i4beg = ebeg >> 2;
    const int i4end = eend >> 2;

    for (int i4 = i4beg + t; i4 < i4end; i4 += 1024) {
        const ivec4 s4 = nt_load_i4(src + 4 * i4);
        const ivec4 d4 = nt_load_i4(dst + 4 * i4);
        #pragma unroll
        for (int k = 0; k < 4; ++k) {
            const unsigned bs = (unsigned)s4[k] / BA;
            const unsigned bd = (unsigned)d4[k] / BA;
            lds_uinc(&c[bucket_of(bs, bd)]);
        }
    }
    __syncthreads();
    if (t < NBK) cnt[bid * NBK + t] = c[t];
}

// ---------------------------------------------------------------------------
// K2: exclusive prefix -> per-(seg,bucket) base, bucket-grouped layout.
// ---------------------------------------------------------------------------
__global__ __launch_bounds__(1024) void pf_prefix(
    const unsigned* __restrict__ cnt, unsigned* __restrict__ base,
    unsigned* __restrict__ tileStart)
{
    __shared__ unsigned colTot[NBK], ts[NBK + 1];
    const int t = threadIdx.x;
    if (t < NBK) {
        unsigned run = 0;
        for (int s = 0; s < SEGS; ++s) {
            base[s * NBK + t] = run;         // offset within bucket
            run += cnt[s * NBK + t];
        }
        colTot[t] = run;
    }
    __syncthreads();
    if (t == 0) {
        unsigned run = 0;
        for (int k = 0; k < NBK; ++k) { ts[k] = run; run += colTot[k]; }
        ts[NBK] = run;
    }
    __syncthreads();
    if (t < NBK) {
        const unsigned add = ts[t];
        for (int s = 0; s < SEGS; ++s) base[s * NBK + t] += add;
    }
    if (t <= NBK) tileStart[t] = ts[t];
}

// ---------------------------------------------------------------------------
// K3: place records.
// rec = (sJ<<25)|(sI<<24)|(li<<12)|lj.  Off-diag: li in bin i (slab A, sI=0),
// lj in bin j (slab B, sJ=1). Diag (i,i): both local to bin i; slab = i&1.
// ---------------------------------------------------------------------------
__global__ __launch_bounds__(1024) void pf_place(
    const int* __restrict__ src, const int* __restrict__ dst,
    const unsigned* __restrict__ base, unsigned* __restrict__ recs, int nEdges)
{
    __shared__ unsigned cur[NBK];
    const int t = threadIdx.x;
    const int bid = (int)blockIdx.x;
    if (t < NBK) cur[t] = base[bid * NBK + t];
    __syncthreads();

    const int eblk  = ((nEdges + SEGS - 1) / SEGS + 3) & ~3;
    const int ebeg  = bid * eblk;
    const int eend  = (ebeg + eblk < nEdges) ? (ebeg + eblk) : nEdges;
    const int i4beg = ebeg >> 2;
    const int i4end = eend >> 2;

    for (int i4 = i4beg + t; i4 < i4end; i4 += 1024) {
        const ivec4 s4 = nt_load_i4(src + 4 * i4);
        const ivec4 d4 = nt_load_i4(dst + 4 * i4);
        #pragma unroll
        for (int k = 0; k < 4; ++k) {
            const unsigned su = (unsigned)s4[k], du = (unsigned)d4[k];
            const unsigned bs = su / BA, bd = du / BA;
            unsigned enc, tl;
            if (bs == bd) {
                const unsigned li = su - bs * BA, lj = du - bs * BA;
                const unsigned m = bs & 1u;
                enc = (m << 25) | (m << 24) | (li << 12) | lj;
                tl  = 496u + (bs >> 1);
            } else {
                const unsigned i = min(bs, bd), j = max(bs, bd);
                const unsigned a = (bs < bd) ? su : du;
                const unsigned b = (bs < bd) ? du : su;
                const unsigned li = a - i * BA, lj = b - j * BA;
                enc = (1u << 25) | (li << 12) | lj;
                tl  = ((i * (63u - i)) >> 1) + (j - i - 1u);
            }
            const unsigned idx = lds_uinc(&cur[tl]);
            recs[idx] = enc;
        }
    }
}

// ---------------------------------------------------------------------------
// K4: per-bucket accumulation. Grid = 512 = exactly 2 rounds on 256 CUs.
// LDS: pos slabs A,B [2*BF] | force slabs A,B [2*BF] | energy [16].
// Inner loop: uint4 record load (prefetched) -> 24 LDS reads -> compute ->
// 24 LDS atomics. Reads precede atomics in program order: no hoisting needed.
// ---------------------------------------------------------------------------
__global__ __launch_bounds__(1024, 1) void pf_accum2(
    const float* __restrict__ pos,
    const float* __restrict__ sigma_p, const float* __restrict__ eps_p,
    const unsigned* __restrict__ recs, const unsigned* __restrict__ tileStart,
    float* __restrict__ frep,        // [NBIN][ROW_F]
    float* __restrict__ erep,        // [NBK]
    int nAtoms)
{
    extern __shared__ float sh[];    // [2BF pos | 2BF force | 16 energy]
    const int t = threadIdx.x, lane = t & 63, v = t >> 6;
    const int b = (int)blockIdx.x;

    // decode bucket -> (binA, binB)
    int binA, binB;
    if (b >= 496) { binA = (b - 496) * 2; binB = binA + 1; }
    else {
        int i = 0, r = b;
        while (r >= 31 - i) { r -= 31 - i; ++i; }
        binA = i; binB = i + 1 + r;
    }

    // zero force slabs + energy partials
    for (int k = t; k < (2 * BF + 16) / 4; k += 1024)
        ((float4*)(sh + 2 * BF))[k] = make_float4(0.f, 0.f, 0.f, 0.f);

    // stage positions: slab A = binA, slab B = binB (clamped)
    {
        const int aS = binA * BA;
        int nf = nAtoms - aS; if (nf > BA) nf = BA; if (nf < 0) nf = 0; nf *= 3;
        const float* g = pos + (size_t)aS * 3;
        for (int k = t; k < (nf >> 2); k += 1024) ((float4*)sh)[k] = ((const float4*)g)[k];
        for (int k = (nf & ~3) + t; k < nf; k += 1024) sh[k] = g[k];
    }
    {
        const int aS = binB * BA;
        int nf = nAtoms - aS; if (nf > BA) nf = BA; if (nf < 0) nf = 0; nf *= 3;
        const float* g = pos + (size_t)aS * 3;
        float* d = sh + BF;
        for (int k = t; k < (nf >> 2); k += 1024) ((float4*)d)[k] = ((const float4*)g)[k];
        for (int k = (nf & ~3) + t; k < nf; k += 1024) d[k] = g[k];
    }
    __syncthreads();

    const float sigma = sigma_p[0], eps = eps_p[0];
    const float sig2 = sigma * sigma;
    const float c12 = 12.f * eps, c4 = 4.f * eps;

    const int rBeg = (int)tileStart[b];
    const int rEnd = (int)tileStart[b + 1];
    const uint4* recs4 = (const uint4*)recs;
    const int base4_0 = rBeg >> 2;
    const int i4max   = (rEnd + 3) >> 2;

    float ev = 0.f;
    uint4 curq = make_uint4(0u, 0u, 0u, 0u);
    { const int i4 = base4_0 + t; if (i4 < i4max) curq = recs4[i4]; }

    for (int base4 = base4_0; base4 < i4max; base4 += 1024) {
        const int i4n = base4 + 1024 + t;
        uint4 nxtq = make_uint4(0u, 0u, 0u, 0u);
        if (i4n < i4max) nxtq = recs4[i4n];          // prefetch next round

        const int i4c = base4 + t;
        if (i4c < i4max) {
            const int ri0 = 4 * i4c;
            unsigned rr[4]; bool ac[4]; int ai[4], aj[4];
            float p0x[4], p0y[4], p0z[4], p1x[4], p1y[4], p1z[4];

            // ---- phase 1: decode + ALL LDS reads ----
            #pragma unroll
            for (int k = 0; k < 4; ++k) {
                const unsigned rec = (k == 0) ? curq.x : (k == 1) ? curq.y :
                                     (k == 2) ? curq.z : curq.w;
                const int ri = ri0 + k;
                const bool a = (ri >= rBeg) & (ri < rEnd);
                const unsigned r = a ? rec : 0u;
                ac[k] = a; rr[k] = r;
                const int li = (int)((r >> 12) & 0xFFFu);
                const int lj = (int)(r & 0xFFFu);
                const int oI = (int)((r >> 24) & 1u) * BF;
                const int oJ = (int)((r >> 25) & 1u) * BF;
                const int aI = oI + 3 * li, aJ = oJ + 3 * lj;
                ai[k] = aI; aj[k] = aJ;
                p0x[k] = sh[aI + 0]; p0y[k] = sh[aI + 1]; p0z[k] = sh[aI + 2];
                p1x[k] = sh[aJ + 0]; p1y[k] = sh[aJ + 1]; p1z[k] = sh[aJ + 2];
            }

            // ---- phase 2: compute ----
            float fx[4], fy[4], fz[4];
            #pragma unroll
            for (int k = 0; k < 4; ++k) {
                const float dx = p0x[k] - p1x[k];
                const float dy = p0y[k] - p1y[k];
                const float dz = p0z[k] - p1z[k];
                const float r2   = dx * dx + dy * dy + dz * dz;
                const float ir2  = 1.0f / r2;
                const float s2   = sig2 * ir2;
                const float sr6  = s2 * s2 * s2;
                const float sr12 = sr6 * sr6;
                const float fs   = c12 * (2.f * sr12 - sr6) * ir2;
                fx[k] = fs * dx; fy[k] = fs * dy; fz[k] = fs * dz;
                ev += ac[k] ? c4 * (sr12 - sr6) : 0.f;
            }

            // ---- phase 3: atomics ----
            float* sF = sh + 2 * BF;
            #pragma unroll
            for (int k = 0; k < 4; ++k) {
                if (ac[k]) {
                    lds_fadd(&sF[ai[k] + 0],  fx[k]);
                    lds_fadd(&sF[ai[k] + 1],  fy[k]);
                    lds_fadd(&sF[ai[k] + 2],  fz[k]);
                    lds_fadd(&sF[aj[k] + 0], -fx[k]);
                    lds_fadd(&sF[aj[k] + 1], -fy[k]);
                    lds_fadd(&sF[aj[k] + 2], -fz[k]);
                }
            }
        }
        curq = nxtq;
    }

    #pragma unroll
    for (int off = 32; off > 0; off >>= 1) ev += __shfl_down(ev, off, 64);
    if (lane == 0) sh[4 * BF + v] = ev;
    __syncthreads();

    // flush slabs. Off-diag: fA -> (row binB, bin binA), fB -> (row binA, bin binB).
    // Merged diag: fA -> (row binA, bin binA), fB -> (row binB, bin binB).
    const int rowA = (b < 496) ? binB : binA;
    const int rowB = (b < 496) ? binA : binB;
    float4* dA = (float4*)(frep + (size_t)rowA * ROW_F + (size_t)binA * BF);
    float4* dB = (float4*)(frep + (size_t)rowB * ROW_F + (size_t)binB * BF);
    const float4* sFA = (const float4*)(sh + 2 * BF);
    const float4* sFB = (const float4*)(sh + 3 * BF);
    for (int k = t; k < BF / 4; k += 1024) dA[k] = sFA[k];
    for (int k = t; k < BF / 4; k += 1024) dB[k] = sFB[k];

    if (t == 0) {
        float e = 0.f;
        #pragma unroll
        for (int w = 0; w < 16; ++w) e += sh[4 * BF + w];
        erep[b] = e;
    }
}

// ---------------------------------------------------------------------------
// Shared reduce kernel (rows -> output).
// ---------------------------------------------------------------------------
__global__ __launch_bounds__(256) void pairforce_reduce(
    const float* __restrict__ frep,
    const float* __restrict__ erep,
    float* __restrict__ out,          // [0]=energy, [1..n3]=forces
    int n3, int nChunks, int nPart)
{
    const int i = blockIdx.x * 256 + threadIdx.x;
    if (i < n3) {
        float acc = 0.f;
        for (int c = 0; c < nChunks; ++c)
            acc += frep[(size_t)c * ROW_F + i];
        out[1 + i] = acc;
    }
    if (blockIdx.x == gridDim.x - 1) {      // energy fold
        float e = 0.f;
        for (int jj = threadIdx.x; jj < nPart; jj += 256) e += erep[jj];
        #pragma unroll
        for (int off = 32; off > 0; off >>= 1) e += __shfl_down(e, off, 64);
        __shared__ float ep[4];
        if ((threadIdx.x & 63) == 0) ep[threadIdx.x >> 6] = e;
        __syncthreads();
        if (threadIdx.x == 0) out[0] = ep[0] + ep[1] + ep[2] + ep[3];
    }
}

// ---------------------------------------------------------------------------
// Fallback: R3's binned kernel, verbatim (used only if guards fail).
// ---------------------------------------------------------------------------
__global__ __launch_bounds__(BLOCK, 1) void pairforce_binned(
    const float* __restrict__ pos,
    const float* __restrict__ sigma_p,
    const float* __restrict__ eps_p,
    const int*   __restrict__ src,
    const int*   __restrict__ dst,
    float* __restrict__ frep,
    float* __restrict__ erep,
    int nEdges, int chunkEdges)
{
    extern __shared__ float sh[];
    const int t = threadIdx.x;
    const int b = blockIdx.x % NBINS;
    const int c = blockIdx.x / NBINS;

    for (int jj = t; jj < (BIN_F + 16) / 4; jj += BLOCK)
        ((float4*)sh)[jj] = make_float4(0.f, 0.f, 0.f, 0.f);
    __syncthreads();

    const float sigma = sigma_p[0];
    const float eps   = eps_p[0];
    const float sig2  = sigma * sigma;
    const int binStart = b * BIN_ATOMS;

    const int start = c * chunkEdges;
    const int end   = min(start + chunkEdges, nEdges);

    const int4* src4 = (const int4*)src;
    const int4* dst4 = (const int4*)dst;

    float ev = 0.0f;

    for (int i4 = (start >> 2) + t; i4 < (end >> 2); i4 += BLOCK) {
        const int4 s4 = src4[i4];
        const int4 d4 = dst4[i4];
        #pragma unroll
        for (int k = 0; k < 4; ++k) {
            const int s = (k == 0) ? s4.x : (k == 1) ? s4.y : (k == 2) ? s4.z : s4.w;
            const int d = (k == 0) ? d4.x : (k == 1) ? d4.y : (k == 2) ? d4.z : d4.w;
            const unsigned ls = (unsigned)(s - binStart);
            const unsigned ld = (unsigned)(d - binStart);
            const bool hs = ls < BIN_ATOMS;
            const bool hd = ld < BIN_ATOMS;
            if (hs | hd) {
                const float dx = pos[3 * s + 0] - pos[3 * d + 0];
                const float dy = pos[3 * s + 1] - pos[3 * d + 1];
                const float dz = pos[3 * s + 2] - pos[3 * d + 2];
                const float r2     = dx * dx + dy * dy + dz * dz;
                const float inv_r2 = 1.0f / r2;
                const float s2     = sig2 * inv_r2;
                const float sr6    = s2 * s2 * s2;
                const float sr12   = sr6 * sr6;
                const float fs = 12.0f * eps * (2.0f * sr12 - sr6) * inv_r2;
                const float fx = fs * dx;
                const float fy = fs * dy;
                const float fz = fs * dz;
                if (hs) {
                    atomicAdd(&sh[3 * ls + 0],  fx);
                    atomicAdd(&sh[3 * ls + 1],  fy);
                    atomicAdd(&sh[3 * ls + 2],  fz);
                    ev += 4.0f * eps * (sr12 - sr6);
                }
                if (hd) {
                    atomicAdd(&sh[3 * ld + 0], -fx);
                    atomicAdd(&sh[3 * ld + 1], -fy);
                    atomicAdd(&sh[3 * ld + 2], -fz);
                }
            }
        }
    }

    #pragma unroll
    for (int off = 32; off > 0; off >>= 1)
        ev += __shfl_down(ev, off, 64);
    if ((t & 63) == 0) sh[BIN_F + (t >> 6)] = ev;
    __syncthreads();

    float4* outSeg = (float4*)(frep + (size_t)c * ROW_F + (size_t)b * BIN_F);
    for (int jj = t; jj < BIN_F / 4; jj += BLOCK)
        outSeg[jj] = ((float4*)sh)[jj];

    if (t == 0) {
        float e = 0.f;
        #pragma unroll
        for (int w = 0; w < 16; ++w) e += sh[BIN_F + w];
        erep[blockIdx.x] = e;
    }
}

extern "C" void kernel_launch(void* const* d_in, const int* in_sizes, int n_in,
                              void* d_out, int out_size, void* d_ws, size_t ws_size,
                              hipStream_t stream)
{
    const float* pos     = (const float*)d_in[0];
    const float* sigma_p = (const float*)d_in[1];
    const float* eps_p   = (const float*)d_in[2];
    const int*   edge    = (const int*)d_in[3];

    const int nEdges = in_sizes[3] / 2;      // edge_index is [2, E]
    const int* src = edge;
    const int* dst = edge + nEdges;

    const int n3 = out_size - 1;             // 3*N
    const int nAtoms = n3 / 3;

    // ---- workspace layout (~67 MB, proven fit) ----
    auto alignup = [](size_t x) { return (x + 255) & ~(size_t)255; };
    size_t off = 0;
    unsigned* recs   = (unsigned*)((char*)d_ws + off); off = alignup(off + (size_t)nEdges * 4);
    unsigned* cntp   = (unsigned*)((char*)d_ws + off); off = alignup(off + (size_t)SEGS * NBK * 4);
    unsigned* basep  = (unsigned*)((char*)d_ws + off); off = alignup(off + (size_t)SEGS * NBK * 4);
    unsigned* tstart = (unsigned*)((char*)d_ws + off); off = alignup(off + (size_t)(NBK + 1) * 4);
    float*    frepN  = (float*)((char*)d_ws + off);    off = alignup(off + (size_t)NBIN * ROW_F * 4);
    float*    erepN  = (float*)((char*)d_ws + off);    off = alignup(off + (size_t)NBK * 4);

    if (ws_size >= off && nAtoms <= NBIN * BA && nEdges > 0 && (nEdges & 3) == 0) {
        pf_count<<<SEGS, 1024, 0, stream>>>(src, dst, cntp, nEdges);
        pf_prefix<<<1, 1024, 0, stream>>>(cntp, basep, tstart);
        pf_place<<<SEGS, 1024, 0, stream>>>(src, dst, basep, recs, nEdges);
        const size_t shb = (size_t)(4 * BF + 16) * sizeof(float);   // 153,664 B
        pf_accum2<<<NBK, 1024, shb, stream>>>(pos, sigma_p, eps_p, recs, tstart,
                                              frepN, erepN, nAtoms);
        pairforce_reduce<<<(n3 + 255) / 256, 256, 0, stream>>>(
            frepN, erepN, (float*)d_out, n3, NBIN, NBK);
        return;
    }

    // ---- fallback: R3 path ----
    const size_t rowBytes = (size_t)ROW_F * sizeof(float);
    int nChunks = (int)((ws_size - 4096) / rowBytes);
    if (nChunks > MAXCHUNKS) nChunks = MAXCHUNKS;
    if (nChunks < 1) nChunks = 1;

    const int chunkEdges = (((nEdges + nChunks - 1) / nChunks) + 3) & ~3;

    float* frep = (float*)d_ws;
    float* erep = frep + (size_t)nChunks * ROW_F;

    const size_t shbytes = (size_t)(BIN_F + 16) * sizeof(float);

    const int grid1 = nChunks * NBINS;
    pairforce_binned<<<grid1, BLOCK, shbytes, stream>>>(
        pos, sigma_p, eps_p, src, dst, frep, erep, nEdges, chunkEdges);

    const int grid2 = (n3 + 255) / 256;
    pairforce_reduce<<<grid2, 256, 0, stream>>>(
        frep, erep, (float*)d_out, n3, nChunks, nChunks * NBINS);
}